// Round 10
// baseline (166.739 us; speedup 1.0000x reference)
//
#include <hip/hip_runtime.h>
#include <hip/hip_bf16.h>
#include <math.h>

#define M_GT 20
#define EPSF 1e-6f
#define B_IMG 32
#define NPAIR 96         // 32 images * 3 scales
#define TIE_CAP 2048

// Order-preserving float->uint key (handles negative logits).
__device__ __forceinline__ unsigned keyof(unsigned bits) {
    return (bits & 0x80000000u) ? ~bits : (bits | 0x80000000u);
}
__device__ __forceinline__ float softplus_ref(float x) {
    // exact reference formula for negatives: max(x,0) + log1p(exp(-|x|))
    return fmaxf(x, 0.f) + log1pf(expf(-fabsf(x)));
}

// Inclusive suffix-scan over 1024 threads (16 waves): intra-wave shfl suffix
// + wave-total combine. Returns sum x[tid..1023]; *tot_out = block total.
// Entry barrier protects wtot reuse across consecutive calls.
__device__ __forceinline__ int suffix_scan_1024(int x, int* wtot, int tid, int* tot_out) {
    const int lane = tid & 63, w = tid >> 6;
    int v = x;
    #pragma unroll
    for (int off = 1; off < 64; off <<= 1) {
        int u = __shfl_down(v, off);
        if (lane + off < 64) v += u;
    }
    __syncthreads();
    if (lane == 0) wtot[w] = v;
    __syncthreads();
    int add = 0, tot = 0;
    #pragma unroll
    for (int j = 0; j < 16; ++j) {
        int t = wtot[j];
        tot += t;
        if (j > w) add += t;
    }
    *tot_out = tot;
    return v + add;
}

__device__ __forceinline__ float wave_reduce_f(float v) {
    #pragma unroll
    for (int off = 32; off > 0; off >>= 1) v += __shfl_down(v, off);
    return v;
}

// ---------------------------------------------------------------------------
// One block = one (image,scale) pair, end to end:
//  A) wave-parallel per-chunk GT culling lists (exact: culled GTs have IoU==0)
//  B) match: gate + IoU, pos losses in regs, neg flags -> 48-bit reg mask,
//     12-bit key histogram of negative logits inline (LDS)
//  C) suffix-scan -> k-th-largest threshold bin
//  D) pass B: reload obj planes (L1/L2-hot) where neg-bit set; softplus-sum
//     above threshold bin; gather tie-bin values to LDS
//  E) exact 2x10-bit tie radix (reference tie semantics: kr * softplus(tau))
//  F) block-reduce -> 6-float slot (plain stores; final kernel reduces)
// Selection on raw logits is exact (softplus strictly monotone). Anchor coords
// computed analytically == make_anchors bit-exact. Gate: anchors share center;
// a=2 box contains a=0,1, so zero intersection with it => all IoUs exactly 0.
// ---------------------------------------------------------------------------
template<int H, int NCH>
__device__ __forceinline__ void pair_impl(
    const float* __restrict__ pred,   // this image's (24,H,H) base
    const float4* __restrict__ gtb,   // this image's 20 GT boxes
    const int*   __restrict__ gtl,    // this image's 20 labels
    float* __restrict__ slot,         // 8 floats for this pair
    int* hist, float* ties, float4* sbox, float* sag, int* slab, int* snk,
    int* wtot, float* wpart, int* smisc)
{
    constexpr int HW = H * H;
    constexpr float STRIDE = 256.0f / (float)H;
    constexpr int RPC = 1024 / H;     // rows covered per 1024-pixel chunk
    const int tid = threadIdx.x;
    const int lane = tid & 63, wv = tid >> 6;

    for (int i = tid; i < 4096; i += 1024) hist[i] = 0;
    if (tid == 0) smisc[0] = 0;       // tie gather count

    // A) wave wv builds the culled GT list for chunk wv (order-preserving).
    if (wv < NCH) {
        bool keep = false;
        float4 g = make_float4(0.f, 0.f, 0.f, 0.f);
        int lab = 0;
        if (lane < M_GT) {
            g = gtb[lane]; lab = gtl[lane];
            const float lo = ((float)(wv * RPC) + 0.5f) * STRIDE - 2.0f * STRIDE;
            const float hi = ((float)(wv * RPC + RPC - 1) + 0.5f) * STRIDE + 2.0f * STRIDE;
            keep = (g.y < hi) && (g.w > lo);   // y-overlap possible
        }
        unsigned long long m = __ballot(keep);
        if (keep) {
            int posi = __popcll(m & ((1ull << lane) - 1ull));
            sbox[wv * M_GT + posi] = g;
            sag [wv * M_GT + posi] = (g.z - g.x) * (g.w - g.y);
            slab[wv * M_GT + posi] = lab;
        }
        if (lane == 0) snk[wv] = __popcll(m);
    }
    __syncthreads();

    // B) match
    unsigned long long negbits = 0ull;
    float l_obj = 0.f, l_cls = 0.f, l_loc = 0.f;
    int l_pos = 0;

    for (int c = 0; c < NCH; ++c) {
        const int pix = c * 1024 + tid;
        const int x = pix & (H - 1);
        const int y = pix / H;
        const float cx = ((float)x + 0.5f) * STRIDE;
        const float cy = ((float)y + 0.5f) * STRIDE;
        const int nk = snk[c];
        const float axL1 = cx - 2.f * STRIDE, ayL1 = cy - 2.f * STRIDE;
        const float axL2 = cx + 2.f * STRIDE, ayL2 = cy + 2.f * STRIDE;

        float best[3] = {-1.f, -1.f, -1.f};
        int bj[3] = {0, 0, 0};
        for (int j = 0; j < nk; ++j) {
            const float4 gb = sbox[c * M_GT + j];
            const float glx = fmaxf(axL1, gb.x), gly = fmaxf(ayL1, gb.y);
            const float grx = fminf(axL2, gb.z), gry = fminf(ayL2, gb.w);
            if (grx <= glx || gry <= gly) continue;   // all 3 IoUs exactly 0
            const float ag = sag[c * M_GT + j];
            #pragma unroll
            for (int a = 0; a < 3; ++a) {
                const float half = 0.5f * ((float)(a + 2) * STRIDE);
                const float ax1 = cx - half, ay1 = cy - half;
                const float ax2 = cx + half, ay2 = cy + half;
                const float aa = (ax2 - ax1) * (ay2 - ay1);
                float lx = fmaxf(ax1, gb.x);
                float ly = fmaxf(ay1, gb.y);
                float rx = fminf(ax2, gb.z);
                float ry = fminf(ay2, gb.w);
                float w  = fmaxf(rx - lx, 0.f);
                float h  = fmaxf(ry - ly, 0.f);
                float inter = w * h;
                float iou = inter / (aa + ag - inter + EPSF);
                if (iou > best[a]) { best[a] = iou; bj[a] = j; }   // first-max
            }
        }

        #pragma unroll
        for (int a = 0; a < 3; ++a) {
            const float ba = fmaxf(best[a], 0.f);     // culled/gated give 0
            const bool pos = (ba >= 0.5f);
            const bool neg = (ba < 0.3f);
            const float po = pred[(size_t)(a * 8 + 4) * HW + pix];
            if (neg) {
                negbits |= (1ull << (c * 3 + a));
                atomicAdd(&hist[keyof(__float_as_uint(po)) >> 20], 1);
            }
            if (pos) {
                const int j = bj[a];
                const float half = 0.5f * ((float)(a + 2) * STRIDE);
                const float ax1 = cx - half, ay1 = cy - half;
                const float ax2 = cx + half, ay2 = cy + half;
                l_pos += 1;
                l_obj += fmaxf(po, 0.f) - po + log1pf(expf(-fabsf(po)));  // t=1
                float c0 = pred[(size_t)(a * 8 + 5) * HW + pix];
                float c1 = pred[(size_t)(a * 8 + 6) * HW + pix];
                float c2 = pred[(size_t)(a * 8 + 7) * HW + pix];
                float m2 = fmaxf(c0, fmaxf(c1, c2));
                float lse = m2 + logf(expf(c0 - m2) + expf(c1 - m2) + expf(c2 - m2));
                int tgt = slab[c * M_GT + j];
                float lt = (tgt == 0) ? c0 : ((tgt == 1) ? c1 : c2);
                l_cls += lse - lt;
                float4 gb = sbox[c * M_GT + j];
                float gw = fmaxf(gb.z - gb.x, EPSF), gh = fmaxf(gb.w - gb.y, EPSF);
                float gcx = gb.x + 0.5f * gw, gcy = gb.y + 0.5f * gh;
                float aw = fmaxf(ax2 - ax1, EPSF), ah = fmaxf(ay2 - ay1, EPSF);
                float acx = ax1 + 0.5f * aw, acy = ay1 + 0.5f * ah;
                float tx = (gcx - acx) / (aw + EPSF);
                float ty = (gcy - acy) / (ah + EPSF);
                float tw = logf((gw + EPSF) / (aw + EPSF));
                float th = logf((gh + EPSF) / (ah + EPSF));
                float p0 = pred[(size_t)(a * 8 + 0) * HW + pix];
                float p1 = pred[(size_t)(a * 8 + 1) * HW + pix];
                float p2 = pred[(size_t)(a * 8 + 2) * HW + pix];
                float p3 = pred[(size_t)(a * 8 + 3) * HW + pix];
                float d0 = p0 - tx, d1 = p1 - ty, d2 = p2 - tw, d3 = p3 - th;
                float ad;
                ad = fabsf(d0); l_loc += (ad < 1.f) ? 0.5f * d0 * d0 : ad - 0.5f;
                ad = fabsf(d1); l_loc += (ad < 1.f) ? 0.5f * d1 * d1 : ad - 0.5f;
                ad = fabsf(d2); l_loc += (ad < 1.f) ? 0.5f * d2 * d2 : ad - 0.5f;
                ad = fabsf(d3); l_loc += (ad < 1.f) ? 0.5f * d3 * d3 : ad - 0.5f;
            }
        }
    }
    __syncthreads();   // hist complete

    // C) k and threshold bin
    int postot;
    suffix_scan_1024(l_pos, wtot, tid, &postot);
    const int k = 3 * max(postot, 1);

    const int b0 = tid * 4;
    const int my = hist[b0] + hist[b0 + 1] + hist[b0 + 2] + hist[b0 + 3];
    int nneg;
    const int incl = suffix_scan_1024(my, wtot, tid, &nneg);
    const bool ta = (k >= nneg);
    if (!ta && (incl - my) < k && k <= incl) {      // boundary in my 4 bins
        int cg = incl - my;
        for (int bin = b0 + 3; bin >= b0; --bin) {
            int cc = hist[bin];
            if (cg < k && k <= cg + cc) { smisc[1] = bin; smisc[2] = k - cg; break; }
            cg += cc;
        }
    }
    __syncthreads();
    const int tbin = ta ? 0 : smisc[1];

    // D) pass B: reload obj logits where neg-bit set (L1/L2-hot, same CU)
    float acc = 0.f;
    for (int c = 0; c < NCH; ++c) {
        #pragma unroll
        for (int a = 0; a < 3; ++a) {
            if (negbits & (1ull << (c * 3 + a))) {
                const float v = pred[(size_t)(a * 8 + 4) * HW + c * 1024 + tid];
                const int bin = (int)(keyof(__float_as_uint(v)) >> 20);
                if (ta || bin > tbin) acc += softplus_ref(v);
                else if (bin == tbin) {
                    int idx = atomicAdd(&smisc[0], 1);
                    if (idx < TIE_CAP) ties[idx] = v;
                }
            }
        }
    }
    __syncthreads();   // gathers done; smisc[0] final

    // E) exact tie resolution (two 10-bit LDS radix levels)
    float extra = 0.f;
    const int selcnt = ta ? nneg : k;
    if (!ta) {                                       // ta is block-uniform
        const int m  = min(smisc[0], TIE_CAP);
        const int kr = smisc[2];
        hist[tid] = 0;
        __syncthreads();
        for (int i = tid; i < m; i += 1024)
            atomicAdd(&hist[(keyof(__float_as_uint(ties[i])) >> 10) & 1023], 1);
        __syncthreads();
        {
            int myA = hist[tid], totA;
            int inclA = suffix_scan_1024(myA, wtot, tid, &totA);
            if ((inclA - myA) < kr && kr <= inclA) { smisc[3] = tid; smisc[4] = kr - (inclA - myA); }
        }
        __syncthreads();
        const int binA = smisc[3], krA = smisc[4];
        hist[tid] = 0;
        __syncthreads();
        for (int i = tid; i < m; i += 1024) {
            unsigned key = keyof(__float_as_uint(ties[i]));
            if (((key >> 10) & 1023) == (unsigned)binA) atomicAdd(&hist[key & 1023], 1);
        }
        __syncthreads();
        {
            int myB = hist[tid], totB;
            int inclB = suffix_scan_1024(myB, wtot, tid, &totB);
            if ((inclB - myB) < krA && krA <= inclB) { smisc[5] = tid; smisc[6] = krA - (inclB - myB); }
        }
        __syncthreads();
        const unsigned tkey = (((unsigned)tbin) << 20) | (((unsigned)binA) << 10)
                            | (unsigned)smisc[5];
        float acc2 = 0.f;
        for (int i = tid; i < m; i += 1024) {
            float xv = ties[i];
            if (keyof(__float_as_uint(xv)) > tkey) acc2 += softplus_ref(xv);
        }
        acc2 = wave_reduce_f(acc2);
        __syncthreads();              // protect wpart
        if (lane == 0) wpart[wv] = acc2;
        __syncthreads();
        if (tid == 0) {
            float e2 = 0.f;
            #pragma unroll
            for (int j2 = 0; j2 < 16; ++j2) e2 += wpart[j2];
            const unsigned tb2 = (tkey & 0x80000000u) ? (tkey & 0x7FFFFFFFu) : ~tkey;
            extra = e2 + (float)smisc[6] * softplus_ref(__uint_as_float(tb2));
        }
    }

    // F) block reduce the four float partials, write the pair slot
    float r0 = wave_reduce_f(acc);
    float r1 = wave_reduce_f(l_obj);
    float r2 = wave_reduce_f(l_cls);
    float r3 = wave_reduce_f(l_loc);
    __syncthreads();                  // protect wpart reuse
    if (lane == 0) { wpart[wv] = r0; wpart[16 + wv] = r1; wpart[32 + wv] = r2; wpart[48 + wv] = r3; }
    __syncthreads();
    if (tid == 0) {
        float S0 = 0.f, S1 = 0.f, S2 = 0.f, S3 = 0.f;
        #pragma unroll
        for (int j2 = 0; j2 < 16; ++j2) {
            S0 += wpart[j2]; S1 += wpart[16 + j2]; S2 += wpart[32 + j2]; S3 += wpart[48 + j2];
        }
        slot[0] = S0 + extra;          // selected-negative softplus sum
        slot[1] = (float)selcnt;       // selected-negative count  (< 2^24: exact)
        slot[2] = (float)postot;       // positive count           (< 2^24: exact)
        slot[3] = S1;                  // positive obj loss sum
        slot[4] = S2;                  // cls loss sum
        slot[5] = S3;                  // loc loss sum
    }
}

__global__ __launch_bounds__(1024) void fused_kernel(
    const float* __restrict__ p1, const float* __restrict__ p2,
    const float* __restrict__ p3, const float* __restrict__ gt_boxes,
    const int* __restrict__ gt_labels, float* __restrict__ slots)
{
    __shared__ int    hist[4096];     // 16 KB (reused for tie radix)
    __shared__ float  ties[TIE_CAP];  // 8 KB
    __shared__ float4 sbox[16 * M_GT];
    __shared__ float  sag [16 * M_GT];
    __shared__ int    slab[16 * M_GT];
    __shared__ int    snk [16];
    __shared__ int    wtot[16];
    __shared__ float  wpart[64];
    __shared__ int    smisc[8];

    const int p = blockIdx.x;         // b*3 + s
    const int b = p / 3, s = p % 3;
    const float4* gtb = reinterpret_cast<const float4*>(gt_boxes) + b * M_GT;
    const int* gtl = gt_labels + b * M_GT;
    float* slot = slots + p * 8;

    if (s == 0)
        pair_impl<128, 16>(p1 + (size_t)b * 24 * 128 * 128, gtb, gtl, slot,
                           hist, ties, sbox, sag, slab, snk, wtot, wpart, smisc);
    else if (s == 1)
        pair_impl<64, 4>(p2 + (size_t)b * 24 * 64 * 64, gtb, gtl, slot,
                         hist, ties, sbox, sag, slab, snk, wtot, wpart, smisc);
    else
        pair_impl<32, 1>(p3 + (size_t)b * 24 * 32 * 32, gtb, gtl, slot,
                         hist, ties, sbox, sag, slab, snk, wtot, wpart, smisc);
}

// ---------------------------------------------------------------------------
// Final: reduce 96 slots -> 4 outputs. Cross-kernel visibility via stream order.
// ---------------------------------------------------------------------------
__global__ __launch_bounds__(128) void final_kernel(
    const float* __restrict__ slots, float* __restrict__ out)
{
    const int tid = threadIdx.x;
    float ss = 0.f, sc = 0.f, pp = 0.f, oo = 0.f, cc = 0.f, ll = 0.f;
    if (tid < NPAIR) {
        const float* s = slots + tid * 8;
        ss = s[0]; sc = s[1]; pp = s[2]; oo = s[3]; cc = s[4]; ll = s[5];
    }
    #pragma unroll
    for (int off = 32; off > 0; off >>= 1) {
        ss += __shfl_down(ss, off); sc += __shfl_down(sc, off);
        pp += __shfl_down(pp, off); oo += __shfl_down(oo, off);
        cc += __shfl_down(cc, off); ll += __shfl_down(ll, off);
    }
    __shared__ float sh[12];
    if ((tid & 63) == 0) {
        int w = tid >> 6;
        sh[w * 6 + 0] = ss; sh[w * 6 + 1] = sc; sh[w * 6 + 2] = pp;
        sh[w * 6 + 3] = oo; sh[w * 6 + 4] = cc; sh[w * 6 + 5] = ll;
    }
    __syncthreads();
    if (tid == 0) {
        float SS = sh[0] + sh[6],  SC = sh[1] + sh[7],  P = sh[2] + sh[8];
        float O  = sh[3] + sh[9],  C  = sh[4] + sh[10], L = sh[5] + sh[11];
        float pn = fmaxf(P, 1.f);          // counts are exact integers in fp32
        float on = fmaxf(P + SC, 1.f);
        float lo = (O + SS) / on;
        float lc = C / pn;
        float l2 = L / pn;
        out[0] = lo; out[1] = lc; out[2] = l2;
        out[3] = lo + lc + 2.0f * l2;
    }
}

// ---------------------------------------------------------------------------
extern "C" void kernel_launch(void* const* d_in, const int* in_sizes, int n_in,
                              void* d_out, int out_size, void* d_ws, size_t ws_size,
                              hipStream_t stream) {
    // setup_inputs() dict order: pred1, anchors1, pred2, anchors2, pred3,
    // anchors3, gt_boxes, gt_labels
    const float* pred1     = (const float*)d_in[0];   // (32,24,128,128)
    const float* pred2     = (const float*)d_in[2];   // (32,24,64,64)
    const float* pred3     = (const float*)d_in[4];   // (32,24,32,32)
    const float* gt_boxes  = (const float*)d_in[6];   // (32,20,4)
    const int*   gt_labels = (const int*)d_in[7];     // (32,20)

    float* slots = (float*)d_ws;      // 96 * 8 floats; fully overwritten, no init

    fused_kernel<<<NPAIR, 1024, 0, stream>>>(
        pred1, pred2, pred3, gt_boxes, gt_labels, slots);

    final_kernel<<<1, 128, 0, stream>>>(slots, (float*)d_out);
}